// Round 1
// baseline (1405.828 us; speedup 1.0000x reference)
//
#include <hip/hip_runtime.h>
#include <math.h>

#define TPB 256

// ---------------- CSR build ----------------

__global__ __launch_bounds__(TPB) void k_zero(int* __restrict__ p, int n) {
  int i = blockIdx.x * TPB + threadIdx.x;
  if (i < n) p[i] = 0;
}

__global__ __launch_bounds__(TPB) void k_count(const int* __restrict__ dst,
                                               int* __restrict__ cnt, int nE) {
  int e = blockIdx.x * TPB + threadIdx.x;
  if (e < nE) atomicAdd(&cnt[dst[e]], 1);
}

__global__ __launch_bounds__(TPB) void k_scan1(const int* __restrict__ cnt,
                                               int* __restrict__ bsum, int n) {
  __shared__ int sd[TPB];
  int t = threadIdx.x;
  int base = blockIdx.x * (TPB * 8) + t * 8;
  int s = 0;
#pragma unroll
  for (int j = 0; j < 8; ++j) { int i = base + j; if (i < n) s += cnt[i]; }
  sd[t] = s;
  __syncthreads();
  for (int off = TPB / 2; off > 0; off >>= 1) {
    if (t < off) sd[t] += sd[t + off];
    __syncthreads();
  }
  if (t == 0) bsum[blockIdx.x] = sd[0];
}

__global__ void k_scan2(int* __restrict__ bsum, int* __restrict__ rowPtr, int nb, int n) {
  if (threadIdx.x == 0 && blockIdx.x == 0) {
    int acc = 0;
    for (int i = 0; i < nb; ++i) { int v = bsum[i]; bsum[i] = acc; acc += v; }
    rowPtr[n] = acc;
  }
}

__global__ __launch_bounds__(TPB) void k_scan3(const int* __restrict__ cnt,
                                               const int* __restrict__ bsum,
                                               int* __restrict__ rowPtr,
                                               int* __restrict__ cursor,
                                               float* __restrict__ dinv, int n) {
  __shared__ int sd[TPB];
  int t = threadIdx.x;
  int base = blockIdx.x * (TPB * 8) + t * 8;
  int loc[8];
  int s = 0;
#pragma unroll
  for (int j = 0; j < 8; ++j) {
    int i = base + j;
    int v = (i < n) ? cnt[i] : 0;
    loc[j] = v; s += v;
  }
  sd[t] = s;
  __syncthreads();
  // Hillis-Steele inclusive scan over 256 thread sums
  for (int off = 1; off < TPB; off <<= 1) {
    int add = (t >= off) ? sd[t - off] : 0;
    __syncthreads();
    sd[t] += add;
    __syncthreads();
  }
  int run = bsum[blockIdx.x] + sd[t] - s;  // exclusive prefix for this thread
#pragma unroll
  for (int j = 0; j < 8; ++j) {
    int i = base + j;
    if (i < n) {
      rowPtr[i] = run;
      cursor[i] = run;
      dinv[i]   = 1.0f / sqrtf((float)(loc[j] + 1));  // +1 = self loop
      run += loc[j];
    }
  }
}

__global__ __launch_bounds__(TPB) void k_fill(const int* __restrict__ src,
                                              const int* __restrict__ dst,
                                              int* __restrict__ cursor,
                                              int* __restrict__ col, int nE) {
  int e = blockIdx.x * TPB + threadIdx.x;
  if (e < nE) {
    int d = dst[e];
    int pos = atomicAdd(&cursor[d], 1);
    col[pos] = src[e];
  }
}

// ---------------- per-layer kernels ----------------

// HWS[n][c] = (act(H[n]) @ W)[c] * dinv[n]
__global__ __launch_bounds__(TPB) void k_gemm(const float* __restrict__ H,
                                              const float* __restrict__ W,
                                              const float* __restrict__ dinv,
                                              float* __restrict__ HWS,
                                              int relu, int rows) {
  __shared__ float Wl[64 * 64];
  __shared__ float Hl[32][64];
  for (int i = threadIdx.x; i < 64 * 64; i += TPB) Wl[i] = W[i];
  const int ct = threadIdx.x & 31;  // col thread: cols ct, ct+32
  const int rt = threadIdx.x >> 5;  // row thread: rows rt*4 .. rt*4+3
  const int blockRow0 = blockIdx.x * 128;

  for (int tile = 0; tile < 4; ++tile) {
    int tr0 = blockRow0 + tile * 32;
    if (tr0 >= rows) break;
    __syncthreads();  // protect Hl from previous iteration readers (also fences Wl load on tile 0)
    for (int i = threadIdx.x; i < 32 * 64; i += TPB) {
      int r = i >> 6, k = i & 63;
      int gr = tr0 + r;
      float v = (gr < rows) ? H[gr * 64 + k] : 0.f;
      if (relu) v = fmaxf(v, 0.f);
      Hl[r][k] = v;
    }
    __syncthreads();

    float acc[4][2] = {{0.f, 0.f}, {0.f, 0.f}, {0.f, 0.f}, {0.f, 0.f}};
#pragma unroll
    for (int k = 0; k < 64; ++k) {
      float w0 = Wl[k * 64 + ct];
      float w1 = Wl[k * 64 + ct + 32];
#pragma unroll
      for (int i = 0; i < 4; ++i) {
        float h = Hl[rt * 4 + i][k];
        acc[i][0] = fmaf(h, w0, acc[i][0]);
        acc[i][1] = fmaf(h, w1, acc[i][1]);
      }
    }
#pragma unroll
    for (int i = 0; i < 4; ++i) {
      int gr = tr0 + rt * 4 + i;
      if (gr < rows) {
        float s = dinv[gr];
        HWS[gr * 64 + ct]      = acc[i][0] * s;
        HWS[gr * 64 + ct + 32] = acc[i][1] * s;
      }
    }
  }
}

// OUT[n][c] = dinv[n] * (HWS[n][c] + sum_{e in row n} HWS[col[e]][c]) + bias[c]
__global__ __launch_bounds__(TPB) void k_scatter(const float* __restrict__ HWS,
                                                 const int* __restrict__ rowPtr,
                                                 const int* __restrict__ col,
                                                 const float* __restrict__ dinv,
                                                 const float* __restrict__ bias,
                                                 float* __restrict__ OUT, int n) {
  int wave = blockIdx.x * (TPB / 64) + (threadIdx.x >> 6);
  int lane = threadIdx.x & 63;
  if (wave >= n) return;
  const int node = wave;
  float acc = HWS[node * 64 + lane];  // self loop term (pre-scaled)
  int e0 = rowPtr[node], e1 = rowPtr[node + 1];
  int deg = e1 - e0;
  for (int base = 0; base < deg; base += 64) {
    int m = deg - base; if (m > 64) m = 64;
    int idxv = (lane < m) ? col[e0 + base + lane] : 0;
    int j = 0;
    for (; j + 4 <= m; j += 4) {
      int s0 = __shfl(idxv, j, 64);
      int s1 = __shfl(idxv, j + 1, 64);
      int s2 = __shfl(idxv, j + 2, 64);
      int s3 = __shfl(idxv, j + 3, 64);
      float v0 = HWS[s0 * 64 + lane];
      float v1 = HWS[s1 * 64 + lane];
      float v2 = HWS[s2 * 64 + lane];
      float v3 = HWS[s3 * 64 + lane];
      acc += (v0 + v1) + (v2 + v3);
    }
    for (; j < m; ++j) {
      int s = __shfl(idxv, j, 64);
      acc += HWS[s * 64 + lane];
    }
  }
  OUT[node * 64 + lane] = dinv[node] * acc + bias[lane];
}

// hws1[n] = (relu(H[n]) . Wo) * dinv[n]
__global__ __launch_bounds__(TPB) void k_fdot(const float* __restrict__ H,
                                              const float* __restrict__ Wo,
                                              const float* __restrict__ dinv,
                                              float* __restrict__ hws1, int n) {
  int i = blockIdx.x * TPB + threadIdx.x;
  if (i >= n) return;
  const float4* Hv = (const float4*)(H + (size_t)i * 64);
  float acc = 0.f;
#pragma unroll
  for (int q = 0; q < 16; ++q) {
    float4 v = Hv[q];
    acc += fmaxf(v.x, 0.f) * Wo[4 * q + 0];
    acc += fmaxf(v.y, 0.f) * Wo[4 * q + 1];
    acc += fmaxf(v.z, 0.f) * Wo[4 * q + 2];
    acc += fmaxf(v.w, 0.f) * Wo[4 * q + 3];
  }
  hws1[i] = acc * dinv[i];
}

__global__ __launch_bounds__(TPB) void k_fscat(const float* __restrict__ hws1,
                                               const int* __restrict__ rowPtr,
                                               const int* __restrict__ col,
                                               const float* __restrict__ dinv,
                                               const float* __restrict__ bo,
                                               float* __restrict__ out, int n) {
  int i = blockIdx.x * TPB + threadIdx.x;
  if (i >= n) return;
  float acc = hws1[i];
  int e0 = rowPtr[i], e1 = rowPtr[i + 1];
  for (int e = e0; e < e1; ++e) acc += hws1[col[e]];
  out[i] = dinv[i] * acc + bo[0];
}

// ---------------- launch ----------------

extern "C" void kernel_launch(void* const* d_in, const int* in_sizes, int n_in,
                              void* d_out, int out_size, void* d_ws, size_t ws_size,
                              hipStream_t stream) {
  const float* x   = (const float*)d_in[0];
  const int*   ei  = (const int*)d_in[1];
  const float* W_i = (const float*)d_in[2];
  const float* b_i = (const float*)d_in[3];
  const float* W_h = (const float*)d_in[4];
  const float* b_h = (const float*)d_in[5];
  const float* W_o = (const float*)d_in[6];
  const float* b_o = (const float*)d_in[7];

  const int N = in_sizes[0] / 64;   // 100000
  const int E = in_sizes[1] / 2;    // 2000000
  const int* srcArr = ei;           // edge_index[0]
  const int* dstArr = ei + E;       // edge_index[1]

  char* w = (char*)d_ws;
  auto take = [&](size_t bytes) -> char* {
    char* p = w;
    w += (bytes + 255) & ~(size_t)255;
    return p;
  };
  int*   rowPtr = (int*)take((size_t)(N + 1) * 4);
  int*   cursor = (int*)take((size_t)N * 4);
  int*   col    = (int*)take((size_t)E * 4);
  float* dinv   = (float*)take((size_t)N * 4);
  int*   bsum   = (int*)take(1024);
  float* bufH   = (float*)take((size_t)N * 64 * 4);
  float* bufS   = (float*)take((size_t)N * 64 * 4);
  float* hws1   = (float*)take((size_t)N * 4);
  (void)ws_size; (void)n_in; (void)out_size;

  const int nbN    = (N + TPB - 1) / TPB;
  const int nbE    = (E + TPB - 1) / TPB;
  const int nbScan = (N + TPB * 8 - 1) / (TPB * 8);
  const int nbGemm = (N + 127) / 128;
  const int nbScat = (N + 3) / 4;  // 4 waves per block

  // CSR build + dinv
  k_zero <<<nbN, TPB, 0, stream>>>(cursor, N);
  k_count<<<nbE, TPB, 0, stream>>>(dstArr, cursor, E);
  k_scan1<<<nbScan, TPB, 0, stream>>>(cursor, bsum, N);
  k_scan2<<<1, 64, 0, stream>>>(bsum, rowPtr, nbScan, N);
  k_scan3<<<nbScan, TPB, 0, stream>>>(cursor, bsum, rowPtr, cursor, dinv, N);
  k_fill <<<nbE, TPB, 0, stream>>>(srcArr, dstArr, cursor, col, E);

  // layer 0: x -> bufH
  k_gemm   <<<nbGemm, TPB, 0, stream>>>(x, W_i, dinv, bufS, 0, N);
  k_scatter<<<nbScat, TPB, 0, stream>>>(bufS, rowPtr, col, dinv, b_i, bufH, N);

  // 6 hidden layers
  for (int l = 0; l < 6; ++l) {
    k_gemm   <<<nbGemm, TPB, 0, stream>>>(bufH, W_h + (size_t)l * 64 * 64, dinv, bufS, 1, N);
    k_scatter<<<nbScat, TPB, 0, stream>>>(bufS, rowPtr, col, dinv, b_h + (size_t)l * 64, bufH, N);
  }

  // output layer: 64 -> 1
  k_fdot <<<nbN, TPB, 0, stream>>>(bufH, W_o, dinv, hws1, N);
  k_fscat<<<nbN, TPB, 0, stream>>>(hws1, rowPtr, col, dinv, b_o, (float*)d_out, N);
}

// Round 2
// 1207.697 us; speedup vs baseline: 1.1641x; 1.1641x over previous
//
#include <hip/hip_runtime.h>
#include <math.h>

#define TPB 256
#define BSH 8                  // 256 nodes per bucket (TPB must equal 1<<BSH)
#define BMAX 512               // max buckets (N <= 131072)
#define EPB 4096               // edges per block in hist/bucket passes

// ---------------- CSR build (bucketed, no global random atomics) ----------------

// pass A: coarse histogram of dst by bucket
__global__ __launch_bounds__(TPB) void k_hist(const int* __restrict__ dst,
                                              int* __restrict__ bucketCnt,
                                              int nE, int nbuck) {
  __shared__ int h[BMAX];
  for (int i = threadIdx.x; i < BMAX; i += TPB) h[i] = 0;
  __syncthreads();
  int base = blockIdx.x * EPB;
  for (int i = threadIdx.x; i < EPB; i += TPB) {
    int e = base + i;
    if (e < nE) atomicAdd(&h[dst[e] >> BSH], 1);
  }
  __syncthreads();
  for (int i = threadIdx.x; i < nbuck; i += TPB)
    if (h[i]) atomicAdd(&bucketCnt[i], h[i]);
}

// pass B: scan bucket counts -> bOff[nbuck+1], init gCur, set rowPtr[n]=nE
__global__ __launch_bounds__(BMAX) void k_bscan(const int* __restrict__ bucketCnt,
                                                int* __restrict__ bOff,
                                                int* __restrict__ gCur,
                                                int* __restrict__ rowPtr,
                                                int nbuck, int n, int nE) {
  __shared__ int sd[BMAX];
  int t = threadIdx.x;
  int v = (t < nbuck) ? bucketCnt[t] : 0;
  sd[t] = v;
  __syncthreads();
  for (int off = 1; off < BMAX; off <<= 1) {
    int add = (t >= off) ? sd[t - off] : 0;
    __syncthreads();
    sd[t] += add;
    __syncthreads();
  }
  if (t < nbuck) {
    bOff[t + 1] = sd[t];
    gCur[t] = sd[t] - v;     // exclusive prefix
  }
  if (t == 0) { bOff[0] = 0; rowPtr[n] = nE; }
}

// pass C: scatter packed (src | dlocal<<20) into bucket-sorted pairBuf
__global__ __launch_bounds__(TPB) void k_bucket(const int* __restrict__ src,
                                                const int* __restrict__ dst,
                                                int* __restrict__ gCur,
                                                int* __restrict__ pairBuf,
                                                int nE, int nbuck) {
  __shared__ int   hist[BMAX];
  __shared__ int   baseL[BMAX];
  __shared__ int   sp[EPB];
  __shared__ short sbk[EPB];
  for (int i = threadIdx.x; i < BMAX; i += TPB) hist[i] = 0;
  __syncthreads();
  int cb = blockIdx.x * EPB;
  for (int i = threadIdx.x; i < EPB; i += TPB) {
    int e = cb + i;
    if (e < nE) {
      int s = src[e], d = dst[e];
      int b = d >> BSH;
      sp[i]  = s | ((d & ((1 << BSH) - 1)) << 20);
      sbk[i] = (short)b;
      atomicAdd(&hist[b], 1);
    } else sbk[i] = -1;
  }
  __syncthreads();
  for (int i = threadIdx.x; i < nbuck; i += TPB)
    baseL[i] = hist[i] ? atomicAdd(&gCur[i], hist[i]) : 0;
  __syncthreads();
  for (int i = threadIdx.x; i < BMAX; i += TPB) hist[i] = 0;  // reuse as cursor
  __syncthreads();
  for (int i = threadIdx.x; i < EPB; i += TPB) {
    int b = sbk[i];
    if (b >= 0) {
      int r = atomicAdd(&hist[b], 1);
      pairBuf[baseL[b] + r] = sp[i];
    }
  }
}

// pass D: per-bucket CSR finalize (rowPtr, col, dinv) — all ranking in LDS
__global__ __launch_bounds__(TPB) void k_final(const int* __restrict__ pairBuf,
                                               const int* __restrict__ bOff,
                                               int* __restrict__ rowPtr,
                                               int* __restrict__ col,
                                               float* __restrict__ dinv,
                                               int n) {
  __shared__ int h[TPB];
  __shared__ int ex[TPB];
  int t = threadIdx.x;
  int b = blockIdx.x;
  int p0 = bOff[b], p1 = bOff[b + 1];
  h[t] = 0;
  __syncthreads();
  for (int i = p0 + t; i < p1; i += TPB)
    atomicAdd(&h[pairBuf[i] >> 20], 1);
  __syncthreads();
  int v = h[t];
  ex[t] = v;
  __syncthreads();
  for (int off = 1; off < TPB; off <<= 1) {
    int add = (t >= off) ? ex[t - off] : 0;
    __syncthreads();
    ex[t] += add;
    __syncthreads();
  }
  int excl = ex[t] - v;
  int node = (b << BSH) + t;
  if (node < n) {
    rowPtr[node] = p0 + excl;
    dinv[node]   = rsqrtf((float)(v + 1));  // +1 self loop
  }
  __syncthreads();
  h[t] = excl;  // reuse as per-local-node cursor
  __syncthreads();
  for (int i = p0 + t; i < p1; i += TPB) {
    int p = pairBuf[i];
    int r = atomicAdd(&h[p >> 20], 1);
    col[p0 + r] = p & 0xFFFFF;
  }
}

// ---------------- per-layer kernels ----------------

// HWS[n][c] = (act(H[n]) @ W)[c] * dinv[n]
__global__ __launch_bounds__(TPB) void k_gemm(const float* __restrict__ H,
                                              const float* __restrict__ W,
                                              const float* __restrict__ dinv,
                                              float* __restrict__ HWS,
                                              int relu, int rows) {
  __shared__ float Wl[64 * 64];
  __shared__ float Hl[32][64];
  for (int i = threadIdx.x; i < 64 * 64; i += TPB) Wl[i] = W[i];
  const int ct = threadIdx.x & 31;
  const int rt = threadIdx.x >> 5;
  const int blockRow0 = blockIdx.x * 128;

  for (int tile = 0; tile < 4; ++tile) {
    int tr0 = blockRow0 + tile * 32;
    if (tr0 >= rows) break;
    __syncthreads();
    for (int i = threadIdx.x; i < 32 * 64; i += TPB) {
      int r = i >> 6, k = i & 63;
      int gr = tr0 + r;
      float v = (gr < rows) ? H[gr * 64 + k] : 0.f;
      if (relu) v = fmaxf(v, 0.f);
      Hl[r][k] = v;
    }
    __syncthreads();

    float acc[4][2] = {{0.f, 0.f}, {0.f, 0.f}, {0.f, 0.f}, {0.f, 0.f}};
#pragma unroll
    for (int k = 0; k < 64; ++k) {
      float w0 = Wl[k * 64 + ct];
      float w1 = Wl[k * 64 + ct + 32];
#pragma unroll
      for (int i = 0; i < 4; ++i) {
        float h = Hl[rt * 4 + i][k];
        acc[i][0] = fmaf(h, w0, acc[i][0]);
        acc[i][1] = fmaf(h, w1, acc[i][1]);
      }
    }
#pragma unroll
    for (int i = 0; i < 4; ++i) {
      int gr = tr0 + rt * 4 + i;
      if (gr < rows) {
        float s = dinv[gr];
        HWS[gr * 64 + ct]      = acc[i][0] * s;
        HWS[gr * 64 + ct + 32] = acc[i][1] * s;
      }
    }
  }
}

// OUT[n][c] = dinv[n] * (HWS[n][c] + sum_{e in row n} HWS[col[e]][c]) + bias[c]
__global__ __launch_bounds__(TPB) void k_scatter(const float* __restrict__ HWS,
                                                 const int* __restrict__ rowPtr,
                                                 const int* __restrict__ col,
                                                 const float* __restrict__ dinv,
                                                 const float* __restrict__ bias,
                                                 float* __restrict__ OUT, int n) {
  int wave = blockIdx.x * (TPB / 64) + (threadIdx.x >> 6);
  int lane = threadIdx.x & 63;
  if (wave >= n) return;
  const int node = wave;
  float acc = HWS[node * 64 + lane];  // self loop term (pre-scaled)
  int e0 = rowPtr[node], e1 = rowPtr[node + 1];
  int deg = e1 - e0;
  for (int base = 0; base < deg; base += 64) {
    int m = deg - base; if (m > 64) m = 64;
    int idxv = (lane < m) ? col[e0 + base + lane] : 0;
    int j = 0;
    for (; j + 8 <= m; j += 8) {
      int s0 = __shfl(idxv, j,     64);
      int s1 = __shfl(idxv, j + 1, 64);
      int s2 = __shfl(idxv, j + 2, 64);
      int s3 = __shfl(idxv, j + 3, 64);
      int s4 = __shfl(idxv, j + 4, 64);
      int s5 = __shfl(idxv, j + 5, 64);
      int s6 = __shfl(idxv, j + 6, 64);
      int s7 = __shfl(idxv, j + 7, 64);
      float v0 = HWS[s0 * 64 + lane];
      float v1 = HWS[s1 * 64 + lane];
      float v2 = HWS[s2 * 64 + lane];
      float v3 = HWS[s3 * 64 + lane];
      float v4 = HWS[s4 * 64 + lane];
      float v5 = HWS[s5 * 64 + lane];
      float v6 = HWS[s6 * 64 + lane];
      float v7 = HWS[s7 * 64 + lane];
      acc += ((v0 + v1) + (v2 + v3)) + ((v4 + v5) + (v6 + v7));
    }
    for (; j + 4 <= m; j += 4) {
      int s0 = __shfl(idxv, j,     64);
      int s1 = __shfl(idxv, j + 1, 64);
      int s2 = __shfl(idxv, j + 2, 64);
      int s3 = __shfl(idxv, j + 3, 64);
      float v0 = HWS[s0 * 64 + lane];
      float v1 = HWS[s1 * 64 + lane];
      float v2 = HWS[s2 * 64 + lane];
      float v3 = HWS[s3 * 64 + lane];
      acc += (v0 + v1) + (v2 + v3);
    }
    for (; j < m; ++j) {
      int s = __shfl(idxv, j, 64);
      acc += HWS[s * 64 + lane];
    }
  }
  OUT[node * 64 + lane] = dinv[node] * acc + bias[lane];
}

// hws1[n] = (relu(H[n]) . Wo) * dinv[n]
__global__ __launch_bounds__(TPB) void k_fdot(const float* __restrict__ H,
                                              const float* __restrict__ Wo,
                                              const float* __restrict__ dinv,
                                              float* __restrict__ hws1, int n) {
  int i = blockIdx.x * TPB + threadIdx.x;
  if (i >= n) return;
  const float4* Hv = (const float4*)(H + (size_t)i * 64);
  float acc = 0.f;
#pragma unroll
  for (int q = 0; q < 16; ++q) {
    float4 v = Hv[q];
    acc += fmaxf(v.x, 0.f) * Wo[4 * q + 0];
    acc += fmaxf(v.y, 0.f) * Wo[4 * q + 1];
    acc += fmaxf(v.z, 0.f) * Wo[4 * q + 2];
    acc += fmaxf(v.w, 0.f) * Wo[4 * q + 3];
  }
  hws1[i] = acc * dinv[i];
}

__global__ __launch_bounds__(TPB) void k_fscat(const float* __restrict__ hws1,
                                               const int* __restrict__ rowPtr,
                                               const int* __restrict__ col,
                                               const float* __restrict__ dinv,
                                               const float* __restrict__ bo,
                                               float* __restrict__ out, int n) {
  int i = blockIdx.x * TPB + threadIdx.x;
  if (i >= n) return;
  float acc = hws1[i];
  int e0 = rowPtr[i], e1 = rowPtr[i + 1];
  for (int e = e0; e < e1; ++e) acc += hws1[col[e]];
  out[i] = dinv[i] * acc + bo[0];
}

// ---------------- launch ----------------

extern "C" void kernel_launch(void* const* d_in, const int* in_sizes, int n_in,
                              void* d_out, int out_size, void* d_ws, size_t ws_size,
                              hipStream_t stream) {
  const float* x   = (const float*)d_in[0];
  const int*   ei  = (const int*)d_in[1];
  const float* W_i = (const float*)d_in[2];
  const float* b_i = (const float*)d_in[3];
  const float* W_h = (const float*)d_in[4];
  const float* b_h = (const float*)d_in[5];
  const float* W_o = (const float*)d_in[6];
  const float* b_o = (const float*)d_in[7];

  const int N = in_sizes[0] / 64;   // 100000
  const int E = in_sizes[1] / 2;    // 2000000
  const int* srcArr = ei;           // edge_index[0]
  const int* dstArr = ei + E;       // edge_index[1]
  const int nbuck = (N + (1 << BSH) - 1) >> BSH;   // 391

  char* w = (char*)d_ws;
  auto take = [&](size_t bytes) -> char* {
    char* p = w;
    w += (bytes + 255) & ~(size_t)255;
    return p;
  };
  int*   rowPtr    = (int*)take((size_t)(N + 1) * 4);
  int*   col       = (int*)take((size_t)E * 4);
  float* dinv      = (float*)take((size_t)N * 4);
  int*   bucketCnt = (int*)take((size_t)BMAX * 4);
  int*   bOff      = (int*)take((size_t)(BMAX + 1) * 4);
  int*   gCur      = (int*)take((size_t)BMAX * 4);
  float* bufH      = (float*)take((size_t)N * 64 * 4);
  float* bufS      = (float*)take((size_t)N * 64 * 4);
  float* hws1      = (float*)take((size_t)N * 4);
  int*   pairBuf   = (int*)bufS;   // alias: bufS unused during CSR build
  (void)ws_size; (void)n_in; (void)out_size;

  const int nbN    = (N + TPB - 1) / TPB;
  const int nbEd   = (E + EPB - 1) / EPB;
  const int nbGemm = (N + 127) / 128;
  const int nbScat = (N + 3) / 4;  // 4 waves per block

  // CSR build + dinv
  hipMemsetAsync(bucketCnt, 0, (size_t)BMAX * 4, stream);
  k_hist  <<<nbEd, TPB, 0, stream>>>(dstArr, bucketCnt, E, nbuck);
  k_bscan <<<1, BMAX, 0, stream>>>(bucketCnt, bOff, gCur, rowPtr, nbuck, N, E);
  k_bucket<<<nbEd, TPB, 0, stream>>>(srcArr, dstArr, gCur, pairBuf, E, nbuck);
  k_final <<<nbuck, TPB, 0, stream>>>(pairBuf, bOff, rowPtr, col, dinv, N);

  // layer 0: x -> bufH
  k_gemm   <<<nbGemm, TPB, 0, stream>>>(x, W_i, dinv, bufS, 0, N);
  k_scatter<<<nbScat, TPB, 0, stream>>>(bufS, rowPtr, col, dinv, b_i, bufH, N);

  // 6 hidden layers
  for (int l = 0; l < 6; ++l) {
    k_gemm   <<<nbGemm, TPB, 0, stream>>>(bufH, W_h + (size_t)l * 64 * 64, dinv, bufS, 1, N);
    k_scatter<<<nbScat, TPB, 0, stream>>>(bufS, rowPtr, col, dinv, b_h + (size_t)l * 64, bufH, N);
  }

  // output layer: 64 -> 1
  k_fdot <<<nbN, TPB, 0, stream>>>(bufH, W_o, dinv, hws1, N);
  k_fscat<<<nbN, TPB, 0, stream>>>(hws1, rowPtr, col, dinv, b_o, (float*)d_out, N);
}

// Round 3
// 724.104 us; speedup vs baseline: 1.9415x; 1.6679x over previous
//
#include <hip/hip_runtime.h>
#include <math.h>

#define TPB 256
#define BSH 8                  // 256 nodes per bucket (TPB must equal 1<<BSH)
#define BMAX 512               // max buckets (N <= 131072)
#define EPB 4096               // edges per block in hist/bucket passes

// ---------------- CSR build (bucketed, no global random atomics) ----------------

// pass A: coarse histogram of dst by bucket
__global__ __launch_bounds__(TPB) void k_hist(const int* __restrict__ dst,
                                              int* __restrict__ bucketCnt,
                                              int nE, int nbuck) {
  __shared__ int h[BMAX];
  for (int i = threadIdx.x; i < BMAX; i += TPB) h[i] = 0;
  __syncthreads();
  int base = blockIdx.x * EPB;
  for (int i = threadIdx.x; i < EPB; i += TPB) {
    int e = base + i;
    if (e < nE) atomicAdd(&h[dst[e] >> BSH], 1);
  }
  __syncthreads();
  for (int i = threadIdx.x; i < nbuck; i += TPB)
    if (h[i]) atomicAdd(&bucketCnt[i], h[i]);
}

// pass B: scan bucket counts -> bOff[nbuck+1], init gCur, set rowPtr[n]=nE
__global__ __launch_bounds__(BMAX) void k_bscan(const int* __restrict__ bucketCnt,
                                                int* __restrict__ bOff,
                                                int* __restrict__ gCur,
                                                int* __restrict__ rowPtr,
                                                int nbuck, int n, int nE) {
  __shared__ int sd[BMAX];
  int t = threadIdx.x;
  int v = (t < nbuck) ? bucketCnt[t] : 0;
  sd[t] = v;
  __syncthreads();
  for (int off = 1; off < BMAX; off <<= 1) {
    int add = (t >= off) ? sd[t - off] : 0;
    __syncthreads();
    sd[t] += add;
    __syncthreads();
  }
  if (t < nbuck) {
    bOff[t + 1] = sd[t];
    gCur[t] = sd[t] - v;     // exclusive prefix
  }
  if (t == 0) { bOff[0] = 0; rowPtr[n] = nE; }
}

// pass C: scatter packed (src | dlocal<<20) into bucket-sorted pairBuf
__global__ __launch_bounds__(TPB) void k_bucket(const int* __restrict__ src,
                                                const int* __restrict__ dst,
                                                int* __restrict__ gCur,
                                                int* __restrict__ pairBuf,
                                                int nE, int nbuck) {
  __shared__ int   hist[BMAX];
  __shared__ int   baseL[BMAX];
  __shared__ int   sp[EPB];
  __shared__ short sbk[EPB];
  for (int i = threadIdx.x; i < BMAX; i += TPB) hist[i] = 0;
  __syncthreads();
  int cb = blockIdx.x * EPB;
  for (int i = threadIdx.x; i < EPB; i += TPB) {
    int e = cb + i;
    if (e < nE) {
      int s = src[e], d = dst[e];
      int b = d >> BSH;
      sp[i]  = s | ((d & ((1 << BSH) - 1)) << 20);
      sbk[i] = (short)b;
      atomicAdd(&hist[b], 1);
    } else sbk[i] = -1;
  }
  __syncthreads();
  for (int i = threadIdx.x; i < nbuck; i += TPB)
    baseL[i] = hist[i] ? atomicAdd(&gCur[i], hist[i]) : 0;
  __syncthreads();
  for (int i = threadIdx.x; i < BMAX; i += TPB) hist[i] = 0;  // reuse as cursor
  __syncthreads();
  for (int i = threadIdx.x; i < EPB; i += TPB) {
    int b = sbk[i];
    if (b >= 0) {
      int r = atomicAdd(&hist[b], 1);
      pairBuf[baseL[b] + r] = sp[i];
    }
  }
}

// pass D: per-bucket CSR finalize (rowPtr, col, dinv) — all ranking in LDS
__global__ __launch_bounds__(TPB) void k_final(const int* __restrict__ pairBuf,
                                               const int* __restrict__ bOff,
                                               int* __restrict__ rowPtr,
                                               int* __restrict__ col,
                                               float* __restrict__ dinv,
                                               int n) {
  __shared__ int h[TPB];
  __shared__ int ex[TPB];
  int t = threadIdx.x;
  int b = blockIdx.x;
  int p0 = bOff[b], p1 = bOff[b + 1];
  h[t] = 0;
  __syncthreads();
  for (int i = p0 + t; i < p1; i += TPB)
    atomicAdd(&h[pairBuf[i] >> 20], 1);
  __syncthreads();
  int v = h[t];
  ex[t] = v;
  __syncthreads();
  for (int off = 1; off < TPB; off <<= 1) {
    int add = (t >= off) ? ex[t - off] : 0;
    __syncthreads();
    ex[t] += add;
    __syncthreads();
  }
  int excl = ex[t] - v;
  int node = (b << BSH) + t;
  if (node < n) {
    rowPtr[node] = p0 + excl;
    dinv[node]   = rsqrtf((float)(v + 1));  // +1 self loop
  }
  __syncthreads();
  h[t] = excl;  // reuse as per-local-node cursor
  __syncthreads();
  for (int i = p0 + t; i < p1; i += TPB) {
    int p = pairBuf[i];
    int r = atomicAdd(&h[p >> 20], 1);
    col[p0 + r] = p & 0xFFFFF;
  }
}

// ---------------- per-layer kernels ----------------

// HWS[n][c] = (act(H[n]) @ W)[c] * dinv[n]
// 64 rows per block, 256 threads, per-thread 4 rows x 4 cols register tile.
// W in LDS (row-major, float4 reads), H tile in LDS padded to stride 68
// (2-way bank conflict = free). VGPR capped via launch_bounds -> 4 waves/EU.
__global__ __launch_bounds__(TPB, 4) void k_gemm(const float* __restrict__ H,
                                                 const float* __restrict__ W,
                                                 const float* __restrict__ dinv,
                                                 float* __restrict__ HWS,
                                                 int relu, int rows) {
  __shared__ float Wl[64 * 64];     // [k][c]
  __shared__ float Hl[64][68];      // [r][k], padded
  const int tid = threadIdx.x;
  const int c0 = (tid & 15) * 4;    // 4 consecutive cols
  const int r0 = (tid >> 4) * 4;    // 4 consecutive rows
  const int row0 = blockIdx.x * 64;

  // stage W: 1024 float4, coalesced
  for (int i = tid; i < 64 * 16; i += TPB)
    ((float4*)Wl)[i] = ((const float4*)W)[i];

  // stage H tile: each i -> row i>>4, quad i&15 (fully coalesced 16B/lane)
  for (int i = tid; i < 64 * 16; i += TPB) {
    int r = i >> 4, q = i & 15;
    int gr = row0 + r;
    float4 v = make_float4(0.f, 0.f, 0.f, 0.f);
    if (gr < rows) v = ((const float4*)(H + (size_t)gr * 64))[q];
    if (relu) {
      v.x = fmaxf(v.x, 0.f); v.y = fmaxf(v.y, 0.f);
      v.z = fmaxf(v.z, 0.f); v.w = fmaxf(v.w, 0.f);
    }
    *(float4*)&Hl[r][q * 4] = v;   // 272B row stride: 16B-aligned
  }
  __syncthreads();

  float acc[4][4] = {{0.f,0.f,0.f,0.f},{0.f,0.f,0.f,0.f},
                     {0.f,0.f,0.f,0.f},{0.f,0.f,0.f,0.f}};
#pragma unroll 4
  for (int k = 0; k < 64; ++k) {
    float4 w = *(const float4*)&Wl[k * 64 + c0];
    float h0 = Hl[r0 + 0][k];
    float h1 = Hl[r0 + 1][k];
    float h2 = Hl[r0 + 2][k];
    float h3 = Hl[r0 + 3][k];
    acc[0][0] = fmaf(h0, w.x, acc[0][0]); acc[0][1] = fmaf(h0, w.y, acc[0][1]);
    acc[0][2] = fmaf(h0, w.z, acc[0][2]); acc[0][3] = fmaf(h0, w.w, acc[0][3]);
    acc[1][0] = fmaf(h1, w.x, acc[1][0]); acc[1][1] = fmaf(h1, w.y, acc[1][1]);
    acc[1][2] = fmaf(h1, w.z, acc[1][2]); acc[1][3] = fmaf(h1, w.w, acc[1][3]);
    acc[2][0] = fmaf(h2, w.x, acc[2][0]); acc[2][1] = fmaf(h2, w.y, acc[2][1]);
    acc[2][2] = fmaf(h2, w.z, acc[2][2]); acc[2][3] = fmaf(h2, w.w, acc[2][3]);
    acc[3][0] = fmaf(h3, w.x, acc[3][0]); acc[3][1] = fmaf(h3, w.y, acc[3][1]);
    acc[3][2] = fmaf(h3, w.z, acc[3][2]); acc[3][3] = fmaf(h3, w.w, acc[3][3]);
  }

#pragma unroll
  for (int i = 0; i < 4; ++i) {
    int gr = row0 + r0 + i;
    if (gr < rows) {
      float s = dinv[gr];
      float4 o = make_float4(acc[i][0] * s, acc[i][1] * s,
                             acc[i][2] * s, acc[i][3] * s);
      *(float4*)&HWS[(size_t)gr * 64 + c0] = o;
    }
  }
}

// OUT[n][c] = dinv[n] * (HWS[n][c] + sum_{e in row n} HWS[col[e]][c]) + bias[c]
__global__ __launch_bounds__(TPB) void k_scatter(const float* __restrict__ HWS,
                                                 const int* __restrict__ rowPtr,
                                                 const int* __restrict__ col,
                                                 const float* __restrict__ dinv,
                                                 const float* __restrict__ bias,
                                                 float* __restrict__ OUT, int n) {
  int wave = blockIdx.x * (TPB / 64) + (threadIdx.x >> 6);
  int lane = threadIdx.x & 63;
  if (wave >= n) return;
  const int node = wave;
  float acc = HWS[node * 64 + lane];  // self loop term (pre-scaled)
  int e0 = rowPtr[node], e1 = rowPtr[node + 1];
  int deg = e1 - e0;
  for (int base = 0; base < deg; base += 64) {
    int m = deg - base; if (m > 64) m = 64;
    int idxv = (lane < m) ? col[e0 + base + lane] : 0;
    int j = 0;
    for (; j + 8 <= m; j += 8) {
      int s0 = __shfl(idxv, j,     64);
      int s1 = __shfl(idxv, j + 1, 64);
      int s2 = __shfl(idxv, j + 2, 64);
      int s3 = __shfl(idxv, j + 3, 64);
      int s4 = __shfl(idxv, j + 4, 64);
      int s5 = __shfl(idxv, j + 5, 64);
      int s6 = __shfl(idxv, j + 6, 64);
      int s7 = __shfl(idxv, j + 7, 64);
      float v0 = HWS[s0 * 64 + lane];
      float v1 = HWS[s1 * 64 + lane];
      float v2 = HWS[s2 * 64 + lane];
      float v3 = HWS[s3 * 64 + lane];
      float v4 = HWS[s4 * 64 + lane];
      float v5 = HWS[s5 * 64 + lane];
      float v6 = HWS[s6 * 64 + lane];
      float v7 = HWS[s7 * 64 + lane];
      acc += ((v0 + v1) + (v2 + v3)) + ((v4 + v5) + (v6 + v7));
    }
    for (; j + 4 <= m; j += 4) {
      int s0 = __shfl(idxv, j,     64);
      int s1 = __shfl(idxv, j + 1, 64);
      int s2 = __shfl(idxv, j + 2, 64);
      int s3 = __shfl(idxv, j + 3, 64);
      float v0 = HWS[s0 * 64 + lane];
      float v1 = HWS[s1 * 64 + lane];
      float v2 = HWS[s2 * 64 + lane];
      float v3 = HWS[s3 * 64 + lane];
      acc += (v0 + v1) + (v2 + v3);
    }
    for (; j < m; ++j) {
      int s = __shfl(idxv, j, 64);
      acc += HWS[s * 64 + lane];
    }
  }
  OUT[node * 64 + lane] = dinv[node] * acc + bias[lane];
}

// hws1[n] = (relu(H[n]) . Wo) * dinv[n]
__global__ __launch_bounds__(TPB) void k_fdot(const float* __restrict__ H,
                                              const float* __restrict__ Wo,
                                              const float* __restrict__ dinv,
                                              float* __restrict__ hws1, int n) {
  int i = blockIdx.x * TPB + threadIdx.x;
  if (i >= n) return;
  const float4* Hv = (const float4*)(H + (size_t)i * 64);
  float acc = 0.f;
#pragma unroll
  for (int q = 0; q < 16; ++q) {
    float4 v = Hv[q];
    acc += fmaxf(v.x, 0.f) * Wo[4 * q + 0];
    acc += fmaxf(v.y, 0.f) * Wo[4 * q + 1];
    acc += fmaxf(v.z, 0.f) * Wo[4 * q + 2];
    acc += fmaxf(v.w, 0.f) * Wo[4 * q + 3];
  }
  hws1[i] = acc * dinv[i];
}

__global__ __launch_bounds__(TPB) void k_fscat(const float* __restrict__ hws1,
                                               const int* __restrict__ rowPtr,
                                               const int* __restrict__ col,
                                               const float* __restrict__ dinv,
                                               const float* __restrict__ bo,
                                               float* __restrict__ out, int n) {
  int i = blockIdx.x * TPB + threadIdx.x;
  if (i >= n) return;
  float acc = hws1[i];
  int e0 = rowPtr[i], e1 = rowPtr[i + 1];
  for (int e = e0; e < e1; ++e) acc += hws1[col[e]];
  out[i] = dinv[i] * acc + bo[0];
}

// ---------------- launch ----------------

extern "C" void kernel_launch(void* const* d_in, const int* in_sizes, int n_in,
                              void* d_out, int out_size, void* d_ws, size_t ws_size,
                              hipStream_t stream) {
  const float* x   = (const float*)d_in[0];
  const int*   ei  = (const int*)d_in[1];
  const float* W_i = (const float*)d_in[2];
  const float* b_i = (const float*)d_in[3];
  const float* W_h = (const float*)d_in[4];
  const float* b_h = (const float*)d_in[5];
  const float* W_o = (const float*)d_in[6];
  const float* b_o = (const float*)d_in[7];

  const int N = in_sizes[0] / 64;   // 100000
  const int E = in_sizes[1] / 2;    // 2000000
  const int* srcArr = ei;           // edge_index[0]
  const int* dstArr = ei + E;       // edge_index[1]
  const int nbuck = (N + (1 << BSH) - 1) >> BSH;   // 391

  char* w = (char*)d_ws;
  auto take = [&](size_t bytes) -> char* {
    char* p = w;
    w += (bytes + 255) & ~(size_t)255;
    return p;
  };
  int*   rowPtr    = (int*)take((size_t)(N + 1) * 4);
  int*   col       = (int*)take((size_t)E * 4);
  float* dinv      = (float*)take((size_t)N * 4);
  int*   bucketCnt = (int*)take((size_t)BMAX * 4);
  int*   bOff      = (int*)take((size_t)(BMAX + 1) * 4);
  int*   gCur      = (int*)take((size_t)BMAX * 4);
  float* bufH      = (float*)take((size_t)N * 64 * 4);
  float* bufS      = (float*)take((size_t)N * 64 * 4);
  float* hws1      = (float*)take((size_t)N * 4);
  int*   pairBuf   = (int*)bufS;   // alias: bufS unused during CSR build
  (void)ws_size; (void)n_in; (void)out_size;

  const int nbN    = (N + TPB - 1) / TPB;
  const int nbEd   = (E + EPB - 1) / EPB;
  const int nbGemm = (N + 63) / 64;
  const int nbScat = (N + 3) / 4;  // 4 waves per block

  // CSR build + dinv
  hipMemsetAsync(bucketCnt, 0, (size_t)BMAX * 4, stream);
  k_hist  <<<nbEd, TPB, 0, stream>>>(dstArr, bucketCnt, E, nbuck);
  k_bscan <<<1, BMAX, 0, stream>>>(bucketCnt, bOff, gCur, rowPtr, nbuck, N, E);
  k_bucket<<<nbEd, TPB, 0, stream>>>(srcArr, dstArr, gCur, pairBuf, E, nbuck);
  k_final <<<nbuck, TPB, 0, stream>>>(pairBuf, bOff, rowPtr, col, dinv, N);

  // layer 0: x -> bufH
  k_gemm   <<<nbGemm, TPB, 0, stream>>>(x, W_i, dinv, bufS, 0, N);
  k_scatter<<<nbScat, TPB, 0, stream>>>(bufS, rowPtr, col, dinv, b_i, bufH, N);

  // 6 hidden layers
  for (int l = 0; l < 6; ++l) {
    k_gemm   <<<nbGemm, TPB, 0, stream>>>(bufH, W_h + (size_t)l * 64 * 64, dinv, bufS, 1, N);
    k_scatter<<<nbScat, TPB, 0, stream>>>(bufS, rowPtr, col, dinv, b_h + (size_t)l * 64, bufH, N);
  }

  // output layer: 64 -> 1
  k_fdot <<<nbN, TPB, 0, stream>>>(bufH, W_o, dinv, hws1, N);
  k_fscat<<<nbN, TPB, 0, stream>>>(hws1, rowPtr, col, dinv, b_o, (float*)d_out, N);
}

// Round 5
// 713.455 us; speedup vs baseline: 1.9705x; 1.0149x over previous
//
#include <hip/hip_runtime.h>
#include <math.h>

#define TPB 256
#define BSH 8                  // 256 nodes per bucket (TPB must equal 1<<BSH)
#define BMAX 512               // max buckets (N <= 131072)
#define EPB 4096               // edges per block in hist/bucket passes

// ---------------- CSR build (bucketed, no global random atomics) ----------------

// pass A: coarse histogram of dst by bucket
__global__ __launch_bounds__(TPB) void k_hist(const int* __restrict__ dst,
                                              int* __restrict__ bucketCnt,
                                              int nE, int nbuck) {
  __shared__ int h[BMAX];
  for (int i = threadIdx.x; i < BMAX; i += TPB) h[i] = 0;
  __syncthreads();
  int base = blockIdx.x * EPB;
  for (int i = threadIdx.x; i < EPB; i += TPB) {
    int e = base + i;
    if (e < nE) atomicAdd(&h[dst[e] >> BSH], 1);
  }
  __syncthreads();
  for (int i = threadIdx.x; i < nbuck; i += TPB)
    if (h[i]) atomicAdd(&bucketCnt[i], h[i]);
}

// pass B: scan bucket counts -> bOff[nbuck+1], init gCur, set rowPtr[n]=nE
__global__ __launch_bounds__(BMAX) void k_bscan(const int* __restrict__ bucketCnt,
                                                int* __restrict__ bOff,
                                                int* __restrict__ gCur,
                                                int* __restrict__ rowPtr,
                                                int nbuck, int n, int nE) {
  __shared__ int sd[BMAX];
  int t = threadIdx.x;
  int v = (t < nbuck) ? bucketCnt[t] : 0;
  sd[t] = v;
  __syncthreads();
  for (int off = 1; off < BMAX; off <<= 1) {
    int add = (t >= off) ? sd[t - off] : 0;
    __syncthreads();
    sd[t] += add;
    __syncthreads();
  }
  if (t < nbuck) {
    bOff[t + 1] = sd[t];
    gCur[t] = sd[t] - v;     // exclusive prefix
  }
  if (t == 0) { bOff[0] = 0; rowPtr[n] = nE; }
}

// pass C: scatter packed (src | dlocal<<20) into bucket-sorted pairBuf
__global__ __launch_bounds__(TPB) void k_bucket(const int* __restrict__ src,
                                                const int* __restrict__ dst,
                                                int* __restrict__ gCur,
                                                int* __restrict__ pairBuf,
                                                int nE, int nbuck) {
  __shared__ int   hist[BMAX];
  __shared__ int   baseL[BMAX];
  __shared__ int   sp[EPB];
  __shared__ short sbk[EPB];
  for (int i = threadIdx.x; i < BMAX; i += TPB) hist[i] = 0;
  __syncthreads();
  int cb = blockIdx.x * EPB;
  for (int i = threadIdx.x; i < EPB; i += TPB) {
    int e = cb + i;
    if (e < nE) {
      int s = src[e], d = dst[e];
      int b = d >> BSH;
      sp[i]  = s | ((d & ((1 << BSH) - 1)) << 20);
      sbk[i] = (short)b;
      atomicAdd(&hist[b], 1);
    } else sbk[i] = -1;
  }
  __syncthreads();
  for (int i = threadIdx.x; i < nbuck; i += TPB)
    baseL[i] = hist[i] ? atomicAdd(&gCur[i], hist[i]) : 0;
  __syncthreads();
  for (int i = threadIdx.x; i < BMAX; i += TPB) hist[i] = 0;  // reuse as cursor
  __syncthreads();
  for (int i = threadIdx.x; i < EPB; i += TPB) {
    int b = sbk[i];
    if (b >= 0) {
      int r = atomicAdd(&hist[b], 1);
      pairBuf[baseL[b] + r] = sp[i];
    }
  }
}

// pass D: per-bucket CSR finalize (rowPtr, col, dinv) — all ranking in LDS
__global__ __launch_bounds__(TPB) void k_final(const int* __restrict__ pairBuf,
                                               const int* __restrict__ bOff,
                                               int* __restrict__ rowPtr,
                                               int* __restrict__ col,
                                               float* __restrict__ dinv,
                                               int n) {
  __shared__ int h[TPB];
  __shared__ int ex[TPB];
  int t = threadIdx.x;
  int b = blockIdx.x;
  int p0 = bOff[b], p1 = bOff[b + 1];
  h[t] = 0;
  __syncthreads();
  for (int i = p0 + t; i < p1; i += TPB)
    atomicAdd(&h[pairBuf[i] >> 20], 1);
  __syncthreads();
  int v = h[t];
  ex[t] = v;
  __syncthreads();
  for (int off = 1; off < TPB; off <<= 1) {
    int add = (t >= off) ? ex[t - off] : 0;
    __syncthreads();
    ex[t] += add;
    __syncthreads();
  }
  int excl = ex[t] - v;
  int node = (b << BSH) + t;
  if (node < n) {
    rowPtr[node] = p0 + excl;
    dinv[node]   = rsqrtf((float)(v + 1));  // +1 self loop
  }
  __syncthreads();
  h[t] = excl;  // reuse as per-local-node cursor
  __syncthreads();
  for (int i = p0 + t; i < p1; i += TPB) {
    int p = pairBuf[i];
    int r = atomicAdd(&h[p >> 20], 1);
    col[p0 + r] = p & 0xFFFFF;
  }
}

// ---------------- per-layer kernels ----------------

// HWS[n][c] = (act(H[n]) @ W)[c] * dinv[n]
__global__ __launch_bounds__(TPB, 4) void k_gemm(const float* __restrict__ H,
                                                 const float* __restrict__ W,
                                                 const float* __restrict__ dinv,
                                                 float* __restrict__ HWS,
                                                 int relu, int rows) {
  __shared__ float Wl[64 * 64];     // [k][c]
  __shared__ float Hl[64][68];      // [r][k], padded
  const int tid = threadIdx.x;
  const int c0 = (tid & 15) * 4;    // 4 consecutive cols
  const int r0 = (tid >> 4) * 4;    // 4 consecutive rows
  const int row0 = blockIdx.x * 64;

  for (int i = tid; i < 64 * 16; i += TPB)
    ((float4*)Wl)[i] = ((const float4*)W)[i];

  for (int i = tid; i < 64 * 16; i += TPB) {
    int r = i >> 4, q = i & 15;
    int gr = row0 + r;
    float4 v = make_float4(0.f, 0.f, 0.f, 0.f);
    if (gr < rows) v = ((const float4*)(H + (size_t)gr * 64))[q];
    if (relu) {
      v.x = fmaxf(v.x, 0.f); v.y = fmaxf(v.y, 0.f);
      v.z = fmaxf(v.z, 0.f); v.w = fmaxf(v.w, 0.f);
    }
    *(float4*)&Hl[r][q * 4] = v;
  }
  __syncthreads();

  float acc[4][4] = {{0.f,0.f,0.f,0.f},{0.f,0.f,0.f,0.f},
                     {0.f,0.f,0.f,0.f},{0.f,0.f,0.f,0.f}};
#pragma unroll 4
  for (int k = 0; k < 64; ++k) {
    float4 w = *(const float4*)&Wl[k * 64 + c0];
    float h0 = Hl[r0 + 0][k];
    float h1 = Hl[r0 + 1][k];
    float h2 = Hl[r0 + 2][k];
    float h3 = Hl[r0 + 3][k];
    acc[0][0] = fmaf(h0, w.x, acc[0][0]); acc[0][1] = fmaf(h0, w.y, acc[0][1]);
    acc[0][2] = fmaf(h0, w.z, acc[0][2]); acc[0][3] = fmaf(h0, w.w, acc[0][3]);
    acc[1][0] = fmaf(h1, w.x, acc[1][0]); acc[1][1] = fmaf(h1, w.y, acc[1][1]);
    acc[1][2] = fmaf(h1, w.z, acc[1][2]); acc[1][3] = fmaf(h1, w.w, acc[1][3]);
    acc[2][0] = fmaf(h2, w.x, acc[2][0]); acc[2][1] = fmaf(h2, w.y, acc[2][1]);
    acc[2][2] = fmaf(h2, w.z, acc[2][2]); acc[2][3] = fmaf(h2, w.w, acc[2][3]);
    acc[3][0] = fmaf(h3, w.x, acc[3][0]); acc[3][1] = fmaf(h3, w.y, acc[3][1]);
    acc[3][2] = fmaf(h3, w.z, acc[3][2]); acc[3][3] = fmaf(h3, w.w, acc[3][3]);
  }

#pragma unroll
  for (int i = 0; i < 4; ++i) {
    int gr = row0 + r0 + i;
    if (gr < rows) {
      float s = dinv[gr];
      float4 o = make_float4(acc[i][0] * s, acc[i][1] * s,
                             acc[i][2] * s, acc[i][3] * s);
      *(float4*)&HWS[(size_t)gr * 64 + c0] = o;
    }
  }
}

// OUT[n][c] = dinv[n] * (HWS[n][c] + sum_{e in row n} HWS[col[e]][c]) + bias[c]
// Wave per node. lane = (edge-slot eg = lane>>4, channel-quad q = lane&15).
// One dwordx4 load gathers 4 full 256B rows (1KB) per instruction.
// NOTE: every __shfl sits in wave-uniform control flow (CDNA ds_bpermute
// returns UNDEFINED data when the source lane is exec-inactive — round-4 bug).
__global__ __launch_bounds__(TPB) void k_scatter(const float* __restrict__ HWS,
                                                 const int* __restrict__ rowPtr,
                                                 const int* __restrict__ col,
                                                 const float* __restrict__ dinv,
                                                 const float* __restrict__ bias,
                                                 float* __restrict__ OUT, int n) {
  int wave = blockIdx.x * (TPB / 64) + (threadIdx.x >> 6);
  if (wave >= n) return;
  const int lane = threadIdx.x & 63;
  const int eg = lane >> 4;   // edge slot 0..3
  const int q  = lane & 15;   // channel quad
  const int node = wave;

  float4 acc = make_float4(0.f, 0.f, 0.f, 0.f);
  if (eg == 0)  // self loop counted once
    acc = *(const float4*)&HWS[(size_t)node * 64 + q * 4];

  const int e0 = rowPtr[node];
  const int deg = rowPtr[node + 1] - e0;

  for (int base = 0; base < deg; base += 64) {
    int m = deg - base; if (m > 64) m = 64;
    int idxv = (lane < m) ? col[e0 + base + lane] : 0;
    int j = 0;
    // uniform trip counts: all 64 lanes active at every __shfl below
    for (; j + 16 <= m; j += 16) {
      int s0 = __shfl(idxv, j + eg,      64);
      int s1 = __shfl(idxv, j + 4 + eg,  64);
      int s2 = __shfl(idxv, j + 8 + eg,  64);
      int s3 = __shfl(idxv, j + 12 + eg, 64);
      float4 v0 = *(const float4*)&HWS[(size_t)s0 * 64 + q * 4];
      float4 v1 = *(const float4*)&HWS[(size_t)s1 * 64 + q * 4];
      float4 v2 = *(const float4*)&HWS[(size_t)s2 * 64 + q * 4];
      float4 v3 = *(const float4*)&HWS[(size_t)s3 * 64 + q * 4];
      acc.x += (v0.x + v1.x) + (v2.x + v3.x);
      acc.y += (v0.y + v1.y) + (v2.y + v3.y);
      acc.z += (v0.z + v1.z) + (v2.z + v3.z);
      acc.w += (v0.w + v1.w) + (v2.w + v3.w);
    }
    for (; j + 8 <= m; j += 8) {
      int s0 = __shfl(idxv, j + eg,     64);
      int s1 = __shfl(idxv, j + 4 + eg, 64);
      float4 v0 = *(const float4*)&HWS[(size_t)s0 * 64 + q * 4];
      float4 v1 = *(const float4*)&HWS[(size_t)s1 * 64 + q * 4];
      acc.x += v0.x + v1.x;
      acc.y += v0.y + v1.y;
      acc.z += v0.z + v1.z;
      acc.w += v0.w + v1.w;
    }
    for (; j < m; j += 4) {
      int jj = j + eg;
      int jc = (jj < m) ? jj : (m - 1);     // clamp: source lane always < m
      int s = __shfl(idxv, jc, 64);         // executed by ALL lanes (uniform)
      if (jj < m) {                         // only the gather is predicated
        float4 v = *(const float4*)&HWS[(size_t)s * 64 + q * 4];
        acc.x += v.x; acc.y += v.y; acc.z += v.z; acc.w += v.w;
      }
    }
  }

  // reduce across the 4 edge slots (lanes q, q+16, q+32, q+48)
#pragma unroll
  for (int off = 16; off < 64; off <<= 1) {
    acc.x += __shfl_xor(acc.x, off, 64);
    acc.y += __shfl_xor(acc.y, off, 64);
    acc.z += __shfl_xor(acc.z, off, 64);
    acc.w += __shfl_xor(acc.w, off, 64);
  }

  if (eg == 0) {
    float s = dinv[node];
    float4 b4 = *(const float4*)&bias[q * 4];
    float4 o = make_float4(acc.x * s + b4.x, acc.y * s + b4.y,
                           acc.z * s + b4.z, acc.w * s + b4.w);
    *(float4*)&OUT[(size_t)node * 64 + q * 4] = o;
  }
}

// hws1[n] = (relu(H[n]) . Wo) * dinv[n]
__global__ __launch_bounds__(TPB) void k_fdot(const float* __restrict__ H,
                                              const float* __restrict__ Wo,
                                              const float* __restrict__ dinv,
                                              float* __restrict__ hws1, int n) {
  int i = blockIdx.x * TPB + threadIdx.x;
  if (i >= n) return;
  const float4* Hv = (const float4*)(H + (size_t)i * 64);
  float acc = 0.f;
#pragma unroll
  for (int q = 0; q < 16; ++q) {
    float4 v = Hv[q];
    acc += fmaxf(v.x, 0.f) * Wo[4 * q + 0];
    acc += fmaxf(v.y, 0.f) * Wo[4 * q + 1];
    acc += fmaxf(v.z, 0.f) * Wo[4 * q + 2];
    acc += fmaxf(v.w, 0.f) * Wo[4 * q + 3];
  }
  hws1[i] = acc * dinv[i];
}

__global__ __launch_bounds__(TPB) void k_fscat(const float* __restrict__ hws1,
                                               const int* __restrict__ rowPtr,
                                               const int* __restrict__ col,
                                               const float* __restrict__ dinv,
                                               const float* __restrict__ bo,
                                               float* __restrict__ out, int n) {
  int i = blockIdx.x * TPB + threadIdx.x;
  if (i >= n) return;
  float a0 = hws1[i], a1 = 0.f, a2 = 0.f, a3 = 0.f;
  int e0 = rowPtr[i], e1 = rowPtr[i + 1];
  int e = e0;
  for (; e + 4 <= e1; e += 4) {
    a0 += hws1[col[e]];
    a1 += hws1[col[e + 1]];
    a2 += hws1[col[e + 2]];
    a3 += hws1[col[e + 3]];
  }
  for (; e < e1; ++e) a0 += hws1[col[e]];
  out[i] = dinv[i] * ((a0 + a1) + (a2 + a3)) + bo[0];
}

// ---------------- launch ----------------

extern "C" void kernel_launch(void* const* d_in, const int* in_sizes, int n_in,
                              void* d_out, int out_size, void* d_ws, size_t ws_size,
                              hipStream_t stream) {
  const float* x   = (const float*)d_in[0];
  const int*   ei  = (const int*)d_in[1];
  const float* W_i = (const float*)d_in[2];
  const float* b_i = (const float*)d_in[3];
  const float* W_h = (const float*)d_in[4];
  const float* b_h = (const float*)d_in[5];
  const float* W_o = (const float*)d_in[6];
  const float* b_o = (const float*)d_in[7];

  const int N = in_sizes[0] / 64;   // 100000
  const int E = in_sizes[1] / 2;    // 2000000
  const int* srcArr = ei;           // edge_index[0]
  const int* dstArr = ei + E;       // edge_index[1]
  const int nbuck = (N + (1 << BSH) - 1) >> BSH;   // 391

  char* w = (char*)d_ws;
  auto take = [&](size_t bytes) -> char* {
    char* p = w;
    w += (bytes + 255) & ~(size_t)255;
    return p;
  };
  int*   rowPtr    = (int*)take((size_t)(N + 1) * 4);
  int*   col       = (int*)take((size_t)E * 4);
  float* dinv      = (float*)take((size_t)N * 4);
  int*   bucketCnt = (int*)take((size_t)BMAX * 4);
  int*   bOff      = (int*)take((size_t)(BMAX + 1) * 4);
  int*   gCur      = (int*)take((size_t)BMAX * 4);
  float* bufH      = (float*)take((size_t)N * 64 * 4);
  float* bufS      = (float*)take((size_t)N * 64 * 4);
  float* hws1      = (float*)take((size_t)N * 4);
  int*   pairBuf   = (int*)bufS;   // alias: bufS unused during CSR build
  (void)ws_size; (void)n_in; (void)out_size;

  const int nbN    = (N + TPB - 1) / TPB;
  const int nbEd   = (E + EPB - 1) / EPB;
  const int nbGemm = (N + 63) / 64;
  const int nbScat = (N + 3) / 4;  // 4 waves per block

  // CSR build + dinv
  hipMemsetAsync(bucketCnt, 0, (size_t)BMAX * 4, stream);
  k_hist  <<<nbEd, TPB, 0, stream>>>(dstArr, bucketCnt, E, nbuck);
  k_bscan <<<1, BMAX, 0, stream>>>(bucketCnt, bOff, gCur, rowPtr, nbuck, N, E);
  k_bucket<<<nbEd, TPB, 0, stream>>>(srcArr, dstArr, gCur, pairBuf, E, nbuck);
  k_final <<<nbuck, TPB, 0, stream>>>(pairBuf, bOff, rowPtr, col, dinv, N);

  // layer 0: x -> bufH
  k_gemm   <<<nbGemm, TPB, 0, stream>>>(x, W_i, dinv, bufS, 0, N);
  k_scatter<<<nbScat, TPB, 0, stream>>>(bufS, rowPtr, col, dinv, b_i, bufH, N);

  // 6 hidden layers
  for (int l = 0; l < 6; ++l) {
    k_gemm   <<<nbGemm, TPB, 0, stream>>>(bufH, W_h + (size_t)l * 64 * 64, dinv, bufS, 1, N);
    k_scatter<<<nbScat, TPB, 0, stream>>>(bufS, rowPtr, col, dinv, b_h + (size_t)l * 64, bufH, N);
  }

  // output layer: 64 -> 1
  k_fdot <<<nbN, TPB, 0, stream>>>(bufH, W_o, dinv, hws1, N);
  k_fscat<<<nbN, TPB, 0, stream>>>(hws1, rowPtr, col, dinv, b_o, (float*)d_out, N);
}